// Round 7
// baseline (235.917 us; speedup 1.0000x reference)
//
#include <hip/hip_runtime.h>

typedef unsigned short u16;
typedef unsigned int u32;
typedef __attribute__((ext_vector_type(4))) float f32x4;
typedef __attribute__((ext_vector_type(8))) __bf16 bf16x8;
typedef __attribute__((ext_vector_type(4))) u16 u16x4;
typedef __attribute__((ext_vector_type(2))) u32 u32x2;

// ---------- helpers ----------

__device__ __forceinline__ u16 f2bf(float f) {
  union { float f; unsigned u; } v; v.f = f;
  unsigned r = v.u + 0x7fffu + ((v.u >> 16) & 1u);
  return (u16)(r >> 16);
}

// pack two floats to bf16x2 (round-half-up) via v_perm
__device__ __forceinline__ u32 pack_bf2(float a, float b) {
  union { float f; unsigned u; } x, y;
  x.f = a; y.f = b;
#if __has_builtin(__builtin_amdgcn_perm)
  return __builtin_amdgcn_perm(y.u + 0x8000u, x.u + 0x8000u, 0x07060302u);
#else
  return (u32)((x.u + 0x8000u) >> 16) | ((y.u + 0x8000u) & 0xffff0000u);
#endif
}

__device__ __forceinline__ void stage16(const void* g, void* l) {
#if __has_builtin(__builtin_amdgcn_global_load_lds)
  __builtin_amdgcn_global_load_lds((const __attribute__((address_space(1))) void*)g,
                                   (__attribute__((address_space(3))) void*)l, 16, 0, 0);
#else
  *(f32x4*)l = *(const f32x4*)g;
#endif
}

__device__ __forceinline__ f32x4 mfma16(bf16x8 a, bf16x8 b, f32x4 c) {
  return __builtin_amdgcn_mfma_f32_16x16x32_bf16(a, b, c, 0, 0, 0);
}

__device__ __forceinline__ float fexp2(float x) {
#if __has_builtin(__builtin_amdgcn_exp2f)
  return __builtin_amdgcn_exp2f(x);
#else
  return exp2f(x);
#endif
}

// rope channel select: sections [16,24,24,16,24,24] -> channels 0,1,2,0,1,2
__device__ __forceinline__ int rope_ch(int d) {
  int dd = (d < 64) ? d : d - 64;
  return (dd < 16) ? 0 : (dd < 40 ? 1 : 2);
}

// ---------- kernels ----------

// blocks < 4096: x fp32 -> bf16.  blocks >= 4096: build channel-selected
// rope tables csel/ssel[t][d] = cos/sin[ch(d)][t][d]  (2048x128 each).
__global__ void yuna_convert_prep(const float* __restrict__ in, u16* __restrict__ out,
                                  const float* __restrict__ cosp, const float* __restrict__ sinp,
                                  float* __restrict__ csel, float* __restrict__ ssel) {
  int b = blockIdx.x;
  if (b < 4096) {
    int i = b * 256 + threadIdx.x;
    f32x4 v = ((const f32x4*)in)[i];
    u16x4 o;
    o.x = f2bf(v.x); o.y = f2bf(v.y); o.z = f2bf(v.z); o.w = f2bf(v.w);
    ((u16x4*)out)[i] = o;
  } else {
    int i = (b - 4096) * 256 + threadIdx.x;  // 0..65535, 4 elems each
    int i4 = i * 4;
    int t = i4 >> 7, d = i4 & 127;
    f32x4 c, s;
#pragma unroll
    for (int j = 0; j < 4; ++j) {
      int ch = rope_ch(d + j);
      c[j] = cosp[(size_t)ch * 262144 + (size_t)t * 128 + d + j];
      s[j] = sinp[(size_t)ch * 262144 + (size_t)t * 128 + d + j];
    }
    ((f32x4*)csel)[i] = c;
    ((f32x4*)ssel)[i] = s;
  }
}

// fused weight transpose: out[n][k] = bf16(W[k][n]); all K=2048, ldo=2048
__global__ void yuna_prep_weights(const float* __restrict__ Wq, const float* __restrict__ Wk,
                                  const float* __restrict__ Wv, const float* __restrict__ Wo,
                                  u16* __restrict__ Wb, u16* __restrict__ Wob) {
  __shared__ float tile[64][65];
  const int mat = blockIdx.z;
  const float* W;
  u16* out;
  int N;
  if (mat == 0)      { W = Wq; out = Wb;                          N = 2048; }
  else if (mat == 1) { W = Wk; out = Wb + (size_t)2048 * 2048;    N = 512; }
  else if (mat == 2) { W = Wv; out = Wb + (size_t)2560 * 2048;    N = 512; }
  else               { W = Wo; out = Wob;                         N = 2048; }
  int k0 = blockIdx.x * 64, n0 = blockIdx.y * 64;
  if (n0 >= N) return;
  int tx = threadIdx.x & 63, ty = threadIdx.x >> 6;
#pragma unroll
  for (int j = 0; j < 64; j += 4)
    tile[ty + j][tx] = W[(size_t)(k0 + ty + j) * N + n0 + tx];
  __syncthreads();
#pragma unroll
  for (int j = 0; j < 64; j += 4)
    out[(size_t)(n0 + ty + j) * 2048 + k0 + tx] = f2bf(tile[tx][ty + j]);
}

// Fused QKV GEMM + bias + rope + scatter.  Register-staged pipeline:
// global loads k+1 -> VGPRs during MFMA on LDS tile k; ds_write after barrier.
// Tile 64x128, BK=64, single LDS buffer (24 KB).
// Column mapping: wave w owns cols {w*16..w*16+15} u {w*16+64..w*16+79}.
// by<16 -> Q head, 16..19 -> K head, 20..23 -> V head.
__global__ __launch_bounds__(256, 3) void yuna_gemm_qkv(
    const u16* __restrict__ A, const u16* __restrict__ Bt,
    const float* __restrict__ bq, const float* __restrict__ bk, const float* __restrict__ bv,
    const float* __restrict__ csel, const float* __restrict__ ssel,
    u16* __restrict__ qb, u16* __restrict__ kb, u16* __restrict__ vtb,
    float* __restrict__ pk, float* __restrict__ pv) {
  const int K = 2048;
  __shared__ __align__(16) char As[8192];    // 64x64 bf16, swizzled
  __shared__ __align__(16) char Bs[16384];   // 128x64 bf16, swizzled
  const int tid = threadIdx.x;
  const int wave = tid >> 6, lane = tid & 63;
  const int lrow = lane & 15, lkg = lane >> 4;
  const int m0 = blockIdx.x * 64;
  const int by = blockIdx.y;
  const int n0 = by * 128;
  const int sw = lrow & 7;

  const int srow = tid >> 3;
  const int ssc = (tid & 7) ^ ((tid >> 3) & 7);
  const size_t abase = (size_t)(m0 + srow) * K + ssc * 8;
  const size_t bbase = (size_t)(n0 + srow) * K + ssc * 8;

  const f32x4 fzero = {0.f, 0.f, 0.f, 0.f};
  f32x4 acc[4][2];
#pragma unroll
  for (int mi = 0; mi < 4; ++mi) { acc[mi][0] = fzero; acc[mi][1] = fzero; }

  f32x4 areg[2], breg[4];
  // prologue: load k-tile 0 into regs, write to LDS
#pragma unroll
  for (int it = 0; it < 2; ++it)
    areg[it] = *(const f32x4*)(A + abase + (size_t)it * 32 * K);
#pragma unroll
  for (int it = 0; it < 4; ++it)
    breg[it] = *(const f32x4*)(Bt + bbase + (size_t)it * 32 * K);
#pragma unroll
  for (int it = 0; it < 2; ++it)
    *(f32x4*)(As + (tid + it * 256) * 16) = areg[it];
#pragma unroll
  for (int it = 0; it < 4; ++it)
    *(f32x4*)(Bs + (tid + it * 256) * 16) = breg[it];
  __syncthreads();

  for (int k0 = 0; k0 < K; k0 += 64) {
    const bool more = (k0 + 64 < K);
    if (more) {
#pragma unroll
      for (int it = 0; it < 2; ++it)
        areg[it] = *(const f32x4*)(A + abase + (size_t)it * 32 * K + k0 + 64);
#pragma unroll
      for (int it = 0; it < 4; ++it)
        breg[it] = *(const f32x4*)(Bt + bbase + (size_t)it * 32 * K + k0 + 64);
    }
#pragma unroll
    for (int kk = 0; kk < 2; ++kk) {
      const int cof = ((kk * 4 + lkg) ^ sw) << 4;
      bf16x8 af[4], bfr[2];
#pragma unroll
      for (int mi = 0; mi < 4; ++mi)
        af[mi] = *(const bf16x8*)(As + (mi * 16 + lrow) * 128 + cof);
#pragma unroll
      for (int ni = 0; ni < 2; ++ni)
        bfr[ni] = *(const bf16x8*)(Bs + (wave * 16 + ni * 64 + lrow) * 128 + cof);
#pragma unroll
      for (int mi = 0; mi < 4; ++mi)
#pragma unroll
        for (int ni = 0; ni < 2; ++ni)
          acc[mi][ni] = mfma16(af[mi], bfr[ni], acc[mi][ni]);
    }
    __syncthreads();   // all LDS reads of tile k done
    if (more) {
#pragma unroll
      for (int it = 0; it < 2; ++it)
        *(f32x4*)(As + (tid + it * 256) * 16) = areg[it];   // vmcnt wait lands here
#pragma unroll
      for (int it = 0; it < 4; ++it)
        *(f32x4*)(Bs + (tid + it * 256) * 16) = breg[it];
      __syncthreads();
    }
  }

  // ---- epilogue ----  acc[mi][ni][r]: t = m0+mi*16+lkg*4+r, d = wave*16+ni*64+lrow
  if (by >= 20) {
    const int kvh = by - 20;
#pragma unroll
    for (int mi = 0; mi < 4; ++mi)
#pragma unroll
      for (int ni = 0; ni < 2; ++ni) {
        int d = wave * 16 + ni * 64 + lrow;
        float bb = bv[kvh * 128 + d];
        int mb = mi * 16 + lkg * 4;
        float v0 = acc[mi][ni][0] + bb, v1 = acc[mi][ni][1] + bb;
        float v2 = acc[mi][ni][2] + bb, v3 = acc[mi][ni][3] + bb;
        size_t pb = ((size_t)(kvh * 2048 + m0 + mb)) * 128 + d;
        pv[pb] = v0; pv[pb + 128] = v1; pv[pb + 256] = v2; pv[pb + 384] = v3;
        u16x4 w;
        w.x = f2bf(v0); w.y = f2bf(v1); w.z = f2bf(v2); w.w = f2bf(v3);
        *(u16x4*)(vtb + ((size_t)(kvh * 128 + d)) * 2048 + m0 + mb) = w;
      }
  } else {
    // Q/K: rope entirely in registers (acc[mi][0] = chan d, acc[mi][1] = chan d+64)
    const float QSCALE = 1.4426950408889634f * 0.08838834764831845f;
    const bool isQ = (by < 16);
    const int h = isQ ? by : (by - 16);
    const float* bias = isQ ? bq : bk;
    const int dlo = wave * 16 + lrow;
    const float blo = bias[h * 128 + dlo];
    const float bhi = bias[h * 128 + dlo + 64];
#pragma unroll
    for (int mi = 0; mi < 4; ++mi) {
      const int tb = m0 + mi * 16 + lkg * 4;
#pragma unroll
      for (int r = 0; r < 4; ++r) {
        const int t = tb + r;
        float a = acc[mi][0][r] + blo;
        float b = acc[mi][1][r] + bhi;
        size_t cb = (size_t)t * 128 + dlo;
        float cl = csel[cb], sl = ssel[cb];
        float ch = csel[cb + 64], sh = ssel[cb + 64];
        float lo = a * cl - b * sl;
        float hi = b * ch + a * sh;
        size_t o = (((size_t)(h * 2048 + t)) << 7) + dlo;
        if (isQ) {
          qb[o] = f2bf(lo * QSCALE);
          qb[o + 64] = f2bf(hi * QSCALE);
        } else {
          kb[o] = f2bf(lo);
          kb[o + 64] = f2bf(hi);
          pk[o] = lo; pk[o + 64] = hi;
        }
      }
    }
  }
}

// Output GEMM: C[2048][2048] fp32 = A(yat) @ Wob^T.  Register-staged pipeline.
__global__ __launch_bounds__(256, 3) void yuna_gemm_out(
    const u16* __restrict__ A, const u16* __restrict__ Bt, float* __restrict__ C) {
  const int K = 2048;
  __shared__ __align__(16) char As[8192];
  __shared__ __align__(16) char Bs[16384];
  const int tid = threadIdx.x;
  const int wave = tid >> 6, lane = tid & 63;
  const int lrow = lane & 15, lkg = lane >> 4;
  const int m0 = blockIdx.x * 64;
  const int n0 = blockIdx.y * 128;
  const int wc = wave * 32;
  const int sw = lrow & 7;

  const int srow = tid >> 3;
  const int ssc = (tid & 7) ^ ((tid >> 3) & 7);
  const size_t abase = (size_t)(m0 + srow) * K + ssc * 8;
  const size_t bbase = (size_t)(n0 + srow) * K + ssc * 8;

  const f32x4 fzero = {0.f, 0.f, 0.f, 0.f};
  f32x4 acc[4][2];
#pragma unroll
  for (int mi = 0; mi < 4; ++mi) { acc[mi][0] = fzero; acc[mi][1] = fzero; }

  f32x4 areg[2], breg[4];
#pragma unroll
  for (int it = 0; it < 2; ++it)
    areg[it] = *(const f32x4*)(A + abase + (size_t)it * 32 * K);
#pragma unroll
  for (int it = 0; it < 4; ++it)
    breg[it] = *(const f32x4*)(Bt + bbase + (size_t)it * 32 * K);
#pragma unroll
  for (int it = 0; it < 2; ++it)
    *(f32x4*)(As + (tid + it * 256) * 16) = areg[it];
#pragma unroll
  for (int it = 0; it < 4; ++it)
    *(f32x4*)(Bs + (tid + it * 256) * 16) = breg[it];
  __syncthreads();

  for (int k0 = 0; k0 < K; k0 += 64) {
    const bool more = (k0 + 64 < K);
    if (more) {
#pragma unroll
      for (int it = 0; it < 2; ++it)
        areg[it] = *(const f32x4*)(A + abase + (size_t)it * 32 * K + k0 + 64);
#pragma unroll
      for (int it = 0; it < 4; ++it)
        breg[it] = *(const f32x4*)(Bt + bbase + (size_t)it * 32 * K + k0 + 64);
    }
#pragma unroll
    for (int kk = 0; kk < 2; ++kk) {
      const int cof = ((kk * 4 + lkg) ^ sw) << 4;
      bf16x8 af[4], bfr[2];
#pragma unroll
      for (int mi = 0; mi < 4; ++mi)
        af[mi] = *(const bf16x8*)(As + (mi * 16 + lrow) * 128 + cof);
#pragma unroll
      for (int ni = 0; ni < 2; ++ni)
        bfr[ni] = *(const bf16x8*)(Bs + (wc + ni * 16 + lrow) * 128 + cof);
#pragma unroll
      for (int mi = 0; mi < 4; ++mi)
#pragma unroll
        for (int ni = 0; ni < 2; ++ni)
          acc[mi][ni] = mfma16(af[mi], bfr[ni], acc[mi][ni]);
    }
    __syncthreads();
    if (more) {
#pragma unroll
      for (int it = 0; it < 2; ++it)
        *(f32x4*)(As + (tid + it * 256) * 16) = areg[it];
#pragma unroll
      for (int it = 0; it < 4; ++it)
        *(f32x4*)(Bs + (tid + it * 256) * 16) = breg[it];
      __syncthreads();
    }
  }
#pragma unroll
  for (int mi = 0; mi < 4; ++mi)
#pragma unroll
    for (int ni = 0; ni < 2; ++ni) {
      int d = wc + ni * 16 + lrow;
      int mb = mi * 16 + lkg * 4;
#pragma unroll
      for (int r = 0; r < 4; ++r)
        C[(size_t)(m0 + mb + r) * 2048 + n0 + d] = acc[mi][ni][r];
    }
}

// flash attention, causal, GQA.  S^T formulation.  (unchanged from R6)
__global__ __launch_bounds__(256, 2) void yuna_flash_attn(
    const u16* __restrict__ Q,   // [16][2048][128] pre-scaled
    const u16* __restrict__ Kb,  // [4][2048][128]
    const u16* __restrict__ Vt,  // [4][128][2048]
    u16* __restrict__ Y) {       // [2048][2048]
  __shared__ __align__(16) u16 Ks[2][64 * 128];
  __shared__ __align__(16) u16 Vs[2][128 * 64];
  __shared__ __align__(16) u16 Ps[64 * 64];
  const int h = blockIdx.x;
  const int yb = blockIdx.y;
  const int qb = (yb < 16) ? yb : 47 - yb;
  const int kvh = h >> 2;
  const int tid = threadIdx.x, wave = tid >> 6, lane = tid & 63;
  const int lrow = lane & 15, lkg = lane >> 4;
  const int m = wave * 16 + lrow;
  const int sw = lrow & 7;

  const int krow = tid >> 4;
  const int ksc = (tid & 15) ^ ((tid >> 4) & 7);
  const size_t kbase0 = ((size_t)(kvh * 2048 + krow) << 7) + ksc * 8;
  const int vrow = tid >> 3;
  const int vsc = (tid & 7) ^ ((tid >> 3) & 7);
  const size_t vbase0 = (size_t)(kvh * 128 + vrow) * 2048 + vsc * 8;

  bf16x8 qf[4];
#pragma unroll
  for (int kk = 0; kk < 4; ++kk)
    qf[kk] = *(const bf16x8*)(Q + (((size_t)h * 2048 + qb * 64 + m) << 7) + kk * 32 + lkg * 8);

  const f32x4 fzero = {0.f, 0.f, 0.f, 0.f};
  f32x4 o[8];
#pragma unroll
  for (int dt = 0; dt < 8; ++dt) o[dt] = fzero;
  float m_i = -1e30f, l_i = 0.f;

  const int nkb = qb + 1;

#pragma unroll
  for (int it = 0; it < 4; ++it)
    stage16(Kb + kbase0 + ((size_t)(it * 16) << 7), (char*)Ks[0] + (tid + it * 256) * 16);
#pragma unroll
  for (int it = 0; it < 4; ++it)
    stage16(Vt + vbase0 + (size_t)it * 32 * 2048, (char*)Vs[0] + (tid + it * 256) * 16);

  for (int kb = 0; kb < nkb; ++kb) {
    const int cur = kb & 1;
    const char* Ksb = (const char*)Ks[cur];
    const char* Vsb = (const char*)Vs[cur];
    if (kb + 1 < nkb) {
      char* Ksn = (char*)Ks[cur ^ 1];
      char* Vsn = (char*)Vs[cur ^ 1];
#pragma unroll
      for (int it = 0; it < 4; ++it)
        stage16(Kb + kbase0 + ((size_t)((kb + 1) * 64 + it * 16) << 7), Ksn + (tid + it * 256) * 16);
#pragma unroll
      for (int it = 0; it < 4; ++it)
        stage16(Vt + vbase0 + (size_t)it * 32 * 2048 + (kb + 1) * 64, Vsn + (tid + it * 256) * 16);
      asm volatile("s_waitcnt vmcnt(8)\n\ts_barrier" ::: "memory");
    } else {
      asm volatile("s_waitcnt vmcnt(0)\n\ts_barrier" ::: "memory");
    }

    f32x4 s[4];
#pragma unroll
    for (int nt = 0; nt < 4; ++nt) s[nt] = fzero;
#pragma unroll
    for (int kk = 0; kk < 4; ++kk) {
      const int cof = ((kk * 4 + lkg) ^ sw) << 4;
      bf16x8 kf[4];
#pragma unroll
      for (int nt = 0; nt < 4; ++nt)
        kf[nt] = *(const bf16x8*)(Ksb + (nt * 16 + lrow) * 256 + cof);
#pragma unroll
      for (int nt = 0; nt < 4; ++nt)
        s[nt] = mfma16(kf[nt], qf[kk], s[nt]);
    }
    if (kb == qb) {
#pragma unroll
      for (int nt = 0; nt < 4; ++nt)
#pragma unroll
        for (int r = 0; r < 4; ++r)
          if (nt * 16 + lkg * 4 + r > m) s[nt][r] = -1e30f;
    }

    float mx = -1e30f;
#pragma unroll
    for (int nt = 0; nt < 4; ++nt)
#pragma unroll
      for (int r = 0; r < 4; ++r) mx = fmaxf(mx, s[nt][r]);
    mx = fmaxf(mx, __shfl_xor(mx, 16));
    mx = fmaxf(mx, __shfl_xor(mx, 32));
    float mnew = fmaxf(m_i, mx);
    float alpha = fexp2(m_i - mnew);
    m_i = mnew;
    float ps = 0.f;
    const int hh = lkg & 1;
#pragma unroll
    for (int nt = 0; nt < 4; ++nt) {
      float p0 = fexp2(s[nt][0] - mnew);
      float p1 = fexp2(s[nt][1] - mnew);
      float p2 = fexp2(s[nt][2] - mnew);
      float p3 = fexp2(s[nt][3] - mnew);
      ps += (p0 + p1) + (p2 + p3);
      u32x2 pk2;
      pk2.x = pack_bf2(p0, p1);
      pk2.y = pack_bf2(p2, p3);
      int cc = 2 * nt + (lkg >> 1);
      *(u32x2*)((char*)Ps + m * 128 + ((cc ^ (m & 7)) << 4) + hh * 8) = pk2;
    }
    ps += __shfl_xor(ps, 16);
    ps += __shfl_xor(ps, 32);
    l_i = l_i * alpha + ps;
#pragma unroll
    for (int dt = 0; dt < 8; ++dt) o[dt] *= alpha;

#pragma unroll
    for (int kk = 0; kk < 2; ++kk) {
      const int cof = ((kk * 4 + lkg) ^ sw) << 4;
      bf16x8 pf = *(const bf16x8*)((char*)Ps + m * 128 + cof);
      bf16x8 vf[8];
#pragma unroll
      for (int dt = 0; dt < 8; ++dt)
        vf[dt] = *(const bf16x8*)(Vsb + (dt * 16 + lrow) * 128 + cof);
#pragma unroll
      for (int dt = 0; dt < 8; ++dt)
        o[dt] = mfma16(vf[dt], pf, o[dt]);
    }
    asm volatile("s_barrier" ::: "memory");
  }

  __syncthreads();
  {
    float inv = 1.f / l_i;
    const int hh = lkg & 1;
#pragma unroll
    for (int dt = 0; dt < 8; ++dt) {
      u32x2 w2;
      w2.x = pack_bf2(o[dt][0] * inv, o[dt][1] * inv);
      w2.y = pack_bf2(o[dt][2] * inv, o[dt][3] * inv);
      int cc = 2 * dt + (lkg >> 1);
      *(u32x2*)((char*)Ks[0] + m * 256 + ((cc ^ (m & 7)) << 4) + hh * 8) = w2;
    }
  }
  __syncthreads();
#pragma unroll
  for (int it = 0; it < 4; ++it) {
    int c = tid + it * 256;
    int row = c >> 4, cc = c & 15;
    f32x4 v = *(const f32x4*)((const char*)Ks[0] + row * 256 + ((cc ^ (row & 7)) << 4));
    *(f32x4*)(Y + (size_t)(qb * 64 + row) * 2048 + h * 128 + cc * 8) = v;
  }
}

// ---------- launch ----------

extern "C" void kernel_launch(void* const* d_in, const int* in_sizes, int n_in,
                              void* d_out, int out_size, void* d_ws, size_t ws_size,
                              hipStream_t stream) {
  const float* x = (const float*)d_in[0];
  const float* cosp = (const float*)d_in[1];
  const float* sinp = (const float*)d_in[2];
  const float* Wq = (const float*)d_in[3];
  const float* bq = (const float*)d_in[4];
  const float* Wk = (const float*)d_in[5];
  const float* bk = (const float*)d_in[6];
  const float* Wv = (const float*)d_in[7];
  const float* bv = (const float*)d_in[8];
  const float* Wo = (const float*)d_in[9];
  float* out = (float*)d_out;
  float* out_k = out + 4194304;
  float* out_v = out + 5242880;

  char* ws = (char*)d_ws;
  u16* xb   = (u16*)(ws + 0);          //  8 MB  x  bf16
  u16* Wb   = (u16*)(ws + 8388608);    // 12 MB  fused W^T bf16 [3072][2048]
  u16* Wob  = (u16*)(ws + 20971520);   //  8 MB  Wo^T bf16
  float* csel = (float*)(ws + 29360128); // 1 MB rope cos table [2048][128]
  float* ssel = (float*)(ws + 30408704); // 1 MB rope sin table
  u16* qbuf = (u16*)(ws + 54525952);   //  8 MB  q bf16 [16][2048][128]
  u16* kbuf = (u16*)(ws + 62914560);   //  2 MB  k bf16 [4][2048][128]
  u16* vtb  = (u16*)(ws + 65011712);   //  2 MB  v^T bf16 [4][128][2048]
  u16* yat  = (u16*)(ws + 67108864);   //  8 MB  attn out bf16 [2048][2048]

  yuna_convert_prep<<<4352, 256, 0, stream>>>(x, xb, cosp, sinp, csel, ssel);
  yuna_prep_weights<<<dim3(32, 32, 4), 256, 0, stream>>>(Wq, Wk, Wv, Wo, Wb, Wob);
  yuna_gemm_qkv<<<dim3(32, 24), 256, 0, stream>>>(xb, Wb, bq, bk, bv, csel, ssel,
                                                  qbuf, kbuf, vtb, out_k, out_v);
  yuna_flash_attn<<<dim3(16, 32), 256, 0, stream>>>(qbuf, kbuf, vtb, yat);
  yuna_gemm_out<<<dim3(32, 16), 256, 0, stream>>>(yat, Wob, out);
}